// Round 2
// baseline (235.495 us; speedup 1.0000x reference)
//
#include <hip/hip_runtime.h>

typedef unsigned short u16;
typedef unsigned int   u32;

typedef __attribute__((ext_vector_type(8))) short short8;
typedef __attribute__((ext_vector_type(4))) float floatx4;

// ---- f32 -> bf16 (RNE) ----
__device__ __forceinline__ u16 f2bf(float f) {
    u32 u = __float_as_uint(f);
    u = u + 0x7fffu + ((u >> 16) & 1u);
    return (u16)(u >> 16);
}

__device__ __forceinline__ floatx4 mfma16(short8 a, short8 b, floatx4 c) {
    return __builtin_amdgcn_mfma_f32_16x16x32_bf16(a, b, c, 0, 0, 0);
}

// Stage a [128 rows x 32 cols] bf16 tile from row-major src (leading dim ld elems)
// into padded LDS dst[128][40]. 256 threads, 2x 16B loads each.
__device__ __forceinline__ void stage_tile(const u16* __restrict__ src, int ld,
                                           u16 (*dst)[40], int t) {
    int n0 = t >> 2, c0 = (t & 3) * 8;
    *(uint4*)&dst[n0][c0] = *(const uint4*)(src + n0 * ld + c0);
    int t1 = t + 256;
    int n1 = t1 >> 2, c1 = (t1 & 3) * 8;
    *(uint4*)&dst[n1][c1] = *(const uint4*)(src + n1 * ld + c1);
}

// Per-wave 64x64 MFMA over As/Bs 32-K tiles. Verified gfx950 layouts (m89/m120):
// A-frag: A[m=lane&15][k=(lane>>4)*8+j]; B-frag: B[n=lane&15][k=...];
// C/D: col=lane&15, row=(lane>>4)*4+reg.
__device__ __forceinline__ void mfma_tile(const u16 (*As)[40], const u16 (*Bs)[40],
                                          floatx4 (&acc)[4][4], int mb, int nb,
                                          int lr, int lq) {
    short8 af[4], bfr[4];
#pragma unroll
    for (int i = 0; i < 4; ++i) af[i] = *(const short8*)&As[mb + i * 16 + lr][lq * 8];
#pragma unroll
    for (int j = 0; j < 4; ++j) bfr[j] = *(const short8*)&Bs[nb + j * 16 + lr][lq * 8];
#pragma unroll
    for (int i = 0; i < 4; ++i)
#pragma unroll
        for (int j = 0; j < 4; ++j)
            acc[i][j] = mfma16(af[i], bfr[j], acc[i][j]);
}

// ---- prep: bf16-convert + transpose weights.
// W1Tt[kt][h][kk] = bf16(W1[7+kt*32+kk][h]); W2T[n][k]=bf16(W2[k][n]); W3T[n][k]=bf16(W3[k][n])
__global__ void k_prep(const float* __restrict__ W1, const float* __restrict__ W2,
                       const float* __restrict__ W3, u16* __restrict__ W1Tt,
                       u16* __restrict__ W2T, u16* __restrict__ W3T) {
    int idx = blockIdx.x * 256 + threadIdx.x;
    if (idx < 524288) {
        int kt = idx >> 13;
        int rem = idx & 8191;
        int h = rem >> 5, kk = rem & 31;
        W1Tt[idx] = f2bf(W1[(7 + kt * 32 + kk) * 256 + h]);
    } else if (idx < 589824) {
        int i = idx - 524288;
        int n = i >> 8, k = i & 255;
        W2T[i] = f2bf(W2[k * 256 + n]);
    } else if (idx < 622592) {
        int i = idx - 589824;
        int n = i >> 8, k = i & 255;
        W3T[i] = f2bf(W3[k * 128 + n]);
    }
}

// ---- kernel 1: h1 = lrelu( [u,norm,proj,dots] @ W1 + b1 ), dots generated on the fly
__global__ __launch_bounds__(256, 2) void k_h1(
    const float* __restrict__ x, const float* __restrict__ u,
    const float* __restrict__ basis, const float* __restrict__ W1,
    const float* __restrict__ b1, const u16* __restrict__ W1Tt,
    u16* __restrict__ h1) {
    __shared__ float xs[128][4];
    __shared__ float xjs[2][32][4];
    __shared__ u16 As[128][40];
    __shared__ u16 Bs[128][40];
    __shared__ float rowsml[128][6];
    __shared__ float colsml[128][6];

    const int t = threadIdx.x;
    const int b = blockIdx.z;
    const int i0 = blockIdx.y * 128;
    const int h0 = blockIdx.x * 128;
    const int lane = t & 63, wv = t >> 6;
    const int mb = (wv >> 1) * 64, nb = (wv & 1) * 64;
    const int lr = lane & 15, lq = lane >> 4;

    if (t < 128) {
        int r = t;
        const float* xp = x + (b * 2048 + i0 + r) * 3;
        xs[r][0] = xp[0]; xs[r][1] = xp[1]; xs[r][2] = xp[2];
    } else {
        int c = t - 128;
        float u0 = u[b * 2 + 0], u1 = u[b * 2 + 1];
        int hc = h0 + c;
        colsml[c][0] = b1[hc] + u0 * W1[0 * 256 + hc] + u1 * W1[1 * 256 + hc];
        colsml[c][1] = W1[2 * 256 + hc];
        colsml[c][2] = W1[3 * 256 + hc];
        colsml[c][3] = W1[4 * 256 + hc];
        colsml[c][4] = W1[5 * 256 + hc];
        colsml[c][5] = W1[6 * 256 + hc];
    }
    __syncthreads();
    if (t < 128) {
        int r = t;
        float xx = xs[r][0], xy = xs[r][1], xz = xs[r][2];
        rowsml[r][0] = sqrtf(xx * xx + xy * xy + xz * xz);
#pragma unroll
        for (int p = 0; p < 4; ++p) {
            const float* bp = basis + (b * 4 + p) * 3;
            rowsml[r][1 + p] = xx * bp[0] + xy * bp[1] + xz * bp[2];
        }
    } else if (t < 160) {
        int j = t - 128;
        const float* xp = x + (b * 2048 + j) * 3;
        xjs[0][j][0] = xp[0]; xjs[0][j][1] = xp[1]; xjs[0][j][2] = xp[2];
    }
    __syncthreads();

    floatx4 acc[4][4];
    const floatx4 zero = {0.f, 0.f, 0.f, 0.f};
#pragma unroll
    for (int i = 0; i < 4; ++i)
#pragma unroll
        for (int j = 0; j < 4; ++j) acc[i][j] = zero;

    const int ar = t & 127, acg = t >> 7;
    const float axx = xs[ar][0], axy = xs[ar][1], axz = xs[ar][2];

    for (int kt = 0; kt < 64; ++kt) {
        const int cur = kt & 1;
        // generate dots A-tile: As[r][c] = bf16(sqrt(x_{i0+r} . x_{k0+c}))
        u16 tmp[16];
#pragma unroll
        for (int cc = 0; cc < 16; ++cc) {
            int c = acg * 16 + cc;
            float4 xj = *(const float4*)&xjs[cur][c][0];
            float d = axx * xj.x + axy * xj.y + axz * xj.z;
            tmp[cc] = f2bf(sqrtf(fmaxf(d, 0.f)));
        }
        *(uint4*)&As[ar][acg * 16]     = *(const uint4*)&tmp[0];
        *(uint4*)&As[ar][acg * 16 + 8] = *(const uint4*)&tmp[8];
        // stage W1 dots-tile (K-tiled layout: fully coalesced)
        stage_tile(W1Tt + kt * 8192 + h0 * 32, 32, Bs, t);
        __syncthreads();
        // prefetch next xj block during compute phase
        if (kt < 63 && t < 32) {
            const float* xp = x + (b * 2048 + (kt + 1) * 32 + t) * 3;
            xjs[cur ^ 1][t][0] = xp[0];
            xjs[cur ^ 1][t][1] = xp[1];
            xjs[cur ^ 1][t][2] = xp[2];
        }
        mfma_tile(As, Bs, acc, mb, nb, lr, lq);
        __syncthreads();
    }

    // epilogue: add small features (globals, norm, proj, bias), LeakyReLU, store bf16
#pragma unroll
    for (int i = 0; i < 4; ++i) {
#pragma unroll
        for (int r = 0; r < 4; ++r) {
            int row = mb + i * 16 + lq * 4 + r;
            float nrm = rowsml[row][0];
            float p0 = rowsml[row][1], p1 = rowsml[row][2];
            float p2 = rowsml[row][3], p3 = rowsml[row][4];
            u16* orow = h1 + (b * 2048 + i0 + row) * 256 + h0;
#pragma unroll
            for (int j = 0; j < 4; ++j) {
                int col = nb + j * 16 + lr;
                float v = acc[i][j][r] + colsml[col][0] + nrm * colsml[col][1] +
                          p0 * colsml[col][2] + p1 * colsml[col][3] +
                          p2 * colsml[col][4] + p3 * colsml[col][5];
                v = v > 0.f ? v : 0.01f * v;
                orow[col] = f2bf(v);
            }
        }
    }
}

// ---- kernel 2: h2 = lrelu(h1 @ W2 + b2)
__global__ __launch_bounds__(256, 2) void k_h2(
    const u16* __restrict__ h1, const u16* __restrict__ W2T,
    const float* __restrict__ b2, u16* __restrict__ h2) {
    __shared__ u16 As[128][40];
    __shared__ u16 Bs[128][40];
    __shared__ float colb[128];
    const int t = threadIdx.x;
    const int n0 = blockIdx.x * 128;
    const int m0 = blockIdx.y * 128;
    const int lane = t & 63, wv = t >> 6;
    const int mb = (wv >> 1) * 64, nb = (wv & 1) * 64;
    const int lr = lane & 15, lq = lane >> 4;

    if (t < 128) colb[t] = b2[n0 + t];

    floatx4 acc[4][4];
    const floatx4 zero = {0.f, 0.f, 0.f, 0.f};
#pragma unroll
    for (int i = 0; i < 4; ++i)
#pragma unroll
        for (int j = 0; j < 4; ++j) acc[i][j] = zero;

    for (int kt = 0; kt < 8; ++kt) {
        stage_tile(h1 + m0 * 256 + kt * 32, 256, As, t);
        stage_tile(W2T + n0 * 256 + kt * 32, 256, Bs, t);
        __syncthreads();
        mfma_tile(As, Bs, acc, mb, nb, lr, lq);
        __syncthreads();
    }
#pragma unroll
    for (int i = 0; i < 4; ++i) {
#pragma unroll
        for (int r = 0; r < 4; ++r) {
            int row = mb + i * 16 + lq * 4 + r;
            u16* orow = h2 + (m0 + row) * 256 + n0;
#pragma unroll
            for (int j = 0; j < 4; ++j) {
                int col = nb + j * 16 + lr;
                float v = acc[i][j][r] + colb[col];
                v = v > 0.f ? v : 0.01f * v;
                orow[col] = f2bf(v);
            }
        }
    }
}

// ---- kernel 3: fk = h2 @ W3 + b3, fused reduce accum[b,o,d] += sum_i fk*x
__global__ __launch_bounds__(256, 2) void k_out(
    const u16* __restrict__ h2, const u16* __restrict__ W3T,
    const float* __restrict__ b3, const float* __restrict__ x,
    float* __restrict__ accum) {
    __shared__ u16 As[128][40];
    __shared__ u16 Bs[128][40];
    __shared__ float colb[128];
    __shared__ float xs[128][4];
    __shared__ float red[128][4];
    const int t = threadIdx.x;
    const int m0 = blockIdx.x * 128;
    const int b = m0 >> 11;
    const int i0 = m0 & 2047;
    const int lane = t & 63, wv = t >> 6;
    const int mb = (wv >> 1) * 64, nb = (wv & 1) * 64;
    const int lr = lane & 15, lq = lane >> 4;

    if (t < 128) {
        colb[t] = b3[t];
        const float* xp = x + (b * 2048 + i0 + t) * 3;
        xs[t][0] = xp[0]; xs[t][1] = xp[1]; xs[t][2] = xp[2];
        red[t][0] = 0.f; red[t][1] = 0.f; red[t][2] = 0.f; red[t][3] = 0.f;
    }

    floatx4 acc[4][4];
    const floatx4 zero = {0.f, 0.f, 0.f, 0.f};
#pragma unroll
    for (int i = 0; i < 4; ++i)
#pragma unroll
        for (int j = 0; j < 4; ++j) acc[i][j] = zero;

    for (int kt = 0; kt < 8; ++kt) {
        stage_tile(h2 + m0 * 256 + kt * 32, 256, As, t);
        stage_tile(W3T + kt * 32, 256, Bs, t);
        __syncthreads();
        mfma_tile(As, Bs, acc, mb, nb, lr, lq);
        __syncthreads();
    }

    float s[4][3];
#pragma unroll
    for (int j = 0; j < 4; ++j) { s[j][0] = 0.f; s[j][1] = 0.f; s[j][2] = 0.f; }
#pragma unroll
    for (int i = 0; i < 4; ++i) {
#pragma unroll
        for (int r = 0; r < 4; ++r) {
            int row = mb + i * 16 + lq * 4 + r;
            float x0 = xs[row][0], x1 = xs[row][1], x2 = xs[row][2];
#pragma unroll
            for (int j = 0; j < 4; ++j) {
                int col = nb + j * 16 + lr;
                float fk = acc[i][j][r] + colb[col];
                s[j][0] += fk * x0; s[j][1] += fk * x1; s[j][2] += fk * x2;
            }
        }
    }
#pragma unroll
    for (int j = 0; j < 4; ++j)
#pragma unroll
        for (int d = 0; d < 3; ++d) {
            float v = s[j][d];
            v += __shfl_xor(v, 16);
            v += __shfl_xor(v, 32);
            if (lane < 16) atomicAdd(&red[nb + j * 16 + lane][d], v);
        }
    __syncthreads();
    if (t < 128) {
#pragma unroll
        for (int d = 0; d < 3; ++d)
            atomicAdd(&accum[(b * 128 + t) * 3 + d], red[t][d]);
    }
}

__global__ void k_fin(const float* __restrict__ accum, float* __restrict__ out) {
    int idx = blockIdx.x * 256 + threadIdx.x;
    if (idx < 6144) out[idx] = accum[idx] * (1.0f / 2048.0f);
}

extern "C" void kernel_launch(void* const* d_in, const int* in_sizes, int n_in,
                              void* d_out, int out_size, void* d_ws, size_t ws_size,
                              hipStream_t stream) {
    const float* x     = (const float*)d_in[0];
    const float* u     = (const float*)d_in[1];
    const float* basis = (const float*)d_in[2];
    const float* W1    = (const float*)d_in[3];
    const float* b1    = (const float*)d_in[4];
    const float* W2    = (const float*)d_in[5];
    const float* b2    = (const float*)d_in[6];
    const float* W3    = (const float*)d_in[7];
    const float* b3    = (const float*)d_in[8];
    float* out = (float*)d_out;

    char* ws = (char*)d_ws;
    u16*  W1Tt  = (u16*)ws;                       // 1,048,576 B  [64][256][32]
    u16*  W2T   = (u16*)(ws + 1048576);           //   131,072 B
    u16*  W3T   = (u16*)(ws + 1179648);           //    65,536 B
    u16*  h1    = (u16*)(ws + 1245184);           // 16,777,216 B
    u16*  h2    = (u16*)(ws + 18022400);          // 16,777,216 B
    float* accum = (float*)(ws + 34799616);       //    24,576 B

    hipMemsetAsync(accum, 0, 24576, stream);
    k_prep<<<2432, 256, 0, stream>>>(W1, W2, W3, W1Tt, W2T, W3T);
    k_h1<<<dim3(2, 16, 16), 256, 0, stream>>>(x, u, basis, W1, b1, W1Tt, h1);
    k_h2<<<dim3(2, 256), 256, 0, stream>>>(h1, W2T, b2, h2);
    k_out<<<256, 256, 0, stream>>>(h2, W3T, b3, x, accum);
    k_fin<<<24, 256, 0, stream>>>(accum, out);
}

// Round 3
// 163.953 us; speedup vs baseline: 1.4364x; 1.4364x over previous
//
#include <hip/hip_runtime.h>

typedef unsigned short u16;
typedef unsigned int   u32;

typedef __attribute__((ext_vector_type(8))) short short8;
typedef __attribute__((ext_vector_type(4))) float floatx4;

// ---- f32 -> bf16 (RNE) ----
__device__ __forceinline__ u16 f2bf(float f) {
    u32 u = __float_as_uint(f);
    u = u + 0x7fffu + ((u >> 16) & 1u);
    return (u16)(u >> 16);
}

__device__ __forceinline__ floatx4 mfma16(short8 a, short8 b, floatx4 c) {
    return __builtin_amdgcn_mfma_f32_16x16x32_bf16(a, b, c, 0, 0, 0);
}

// pack two f32 -> two bf16 (round-to-nearest, ties away) in one v_perm
__device__ __forceinline__ u32 pack2bf(float s0, float s1) {
    u32 a = __float_as_uint(s0) + 0x8000u;
    u32 b = __float_as_uint(s1) + 0x8000u;
    return __builtin_amdgcn_perm(b, a, 0x07060302u);  // {b.hi16, a.hi16}
}

// Stage a [128 rows x 32 cols] bf16 tile from row-major src into padded LDS
// dst[128][40]. 256 threads, 2x 16B loads each.
__device__ __forceinline__ void stage_tile(const u16* __restrict__ src, int ld,
                                           u16 (*dst)[40], int t) {
    int n0 = t >> 2, c0 = (t & 3) * 8;
    *(uint4*)&dst[n0][c0] = *(const uint4*)(src + n0 * ld + c0);
    int t1 = t + 256;
    int n1 = t1 >> 2, c1 = (t1 & 3) * 8;
    *(uint4*)&dst[n1][c1] = *(const uint4*)(src + n1 * ld + c1);
}

// Per-wave 64x64 MFMA over 128-row padded tiles (k_h2/k_out).
__device__ __forceinline__ void mfma_tile(const u16 (*As)[40], const u16 (*Bs)[40],
                                          floatx4 (&acc)[4][4], int mb, int nb,
                                          int lr, int lq) {
    short8 af[4], bfr[4];
#pragma unroll
    for (int i = 0; i < 4; ++i) af[i] = *(const short8*)&As[mb + i * 16 + lr][lq * 8];
#pragma unroll
    for (int j = 0; j < 4; ++j) bfr[j] = *(const short8*)&Bs[nb + j * 16 + lr][lq * 8];
#pragma unroll
    for (int i = 0; i < 4; ++i)
#pragma unroll
        for (int j = 0; j < 4; ++j)
            acc[i][j] = mfma16(af[i], bfr[j], acc[i][j]);
}

// ---- prep: bf16-convert + transpose weights.
// W1Tt[kt][h][kk] = bf16(W1[7+kt*32+kk][h]); W2T[n][k]=bf16(W2[k][n]); W3T[n][k]=bf16(W3[k][n])
__global__ void k_prep(const float* __restrict__ W1, const float* __restrict__ W2,
                       const float* __restrict__ W3, u16* __restrict__ W1Tt,
                       u16* __restrict__ W2T, u16* __restrict__ W3T) {
    int idx = blockIdx.x * 256 + threadIdx.x;
    if (idx < 524288) {
        int kt = idx >> 13;
        int rem = idx & 8191;
        int h = rem >> 5, kk = rem & 31;
        W1Tt[idx] = f2bf(W1[(7 + kt * 32 + kk) * 256 + h]);
    } else if (idx < 589824) {
        int i = idx - 524288;
        int n = i >> 8, k = i & 255;
        W2T[i] = f2bf(W2[k * 256 + n]);
    } else if (idx < 622592) {
        int i = idx - 589824;
        int n = i >> 8, k = i & 255;
        W3T[i] = f2bf(W3[k * 128 + n]);
    }
}

// ---- kernel 1: h1 = lrelu( [u,norm,proj,dots] @ W1 + b1 )
// M=64 rows x N=256 (full H) per block; dots generated once, on the fly.
// Gen mapping: lane = row, wave = 8-col slice -> xj wave-uniform (LDS broadcast).
__global__ __launch_bounds__(256, 2) void k_h1(
    const float* __restrict__ x, const float* __restrict__ u,
    const float* __restrict__ basis, const float* __restrict__ W1,
    const float* __restrict__ b1, const u16* __restrict__ W1Tt,
    u16* __restrict__ h1) {
    __shared__ float4 xls4[1536];     // 24 KB: all 2048 points of batch b, packed xyz stream
    __shared__ u16 As[64][40];        // 5 KB   dots tile (padded)
    __shared__ u16 Bs[256][40];       // 20 KB  W1 tile (padded)
    __shared__ float rowsml[64][6];   // 1.5 KB norm+proj per row
    __shared__ float colsml[256][6];  // 6 KB   bias+u-part+small-W1 cols

    const int t = threadIdx.x;
    const int b = blockIdx.y;
    const int i0 = blockIdx.x * 64;
    const int lane = t & 63, wv = t >> 6;
    const int lr = lane & 15, lq = lane >> 4;
    float* xls = (float*)xls4;

    // preload x[b] (6144 floats) into LDS, coalesced float4
    {
        const float4* src = (const float4*)(x + b * 6144);
#pragma unroll
        for (int i = 0; i < 6; ++i) xls4[t + i * 256] = src[t + i * 256];
    }
    // colsml: independent of xls
    {
        int c = t;
        float u0 = u[b * 2 + 0], u1 = u[b * 2 + 1];
        colsml[c][0] = b1[c] + u0 * W1[0 * 256 + c] + u1 * W1[1 * 256 + c];
        colsml[c][1] = W1[2 * 256 + c];
        colsml[c][2] = W1[3 * 256 + c];
        colsml[c][3] = W1[4 * 256 + c];
        colsml[c][4] = W1[5 * 256 + c];
        colsml[c][5] = W1[6 * 256 + c];
    }
    __syncthreads();
    if (t < 64) {
        int r = t;
        float xx = xls[(i0 + r) * 3], xy = xls[(i0 + r) * 3 + 1], xz = xls[(i0 + r) * 3 + 2];
        rowsml[r][0] = sqrtf(xx * xx + xy * xy + xz * xz);
#pragma unroll
        for (int p = 0; p < 4; ++p) {
            const float* bp = basis + (b * 4 + p) * 3;
            rowsml[r][1 + p] = xx * bp[0] + xy * bp[1] + xz * bp[2];
        }
    }
    // this lane's row coords (row = lane)
    const float ax = xls[(i0 + lane) * 3];
    const float ay = xls[(i0 + lane) * 3 + 1];
    const float az = xls[(i0 + lane) * 3 + 2];

    floatx4 acc[4][4];
    const floatx4 zero = {0.f, 0.f, 0.f, 0.f};
#pragma unroll
    for (int i = 0; i < 4; ++i)
#pragma unroll
        for (int j = 0; j < 4; ++j) acc[i][j] = zero;

    const int cbase = wv * 8;  // this wave's 8-col slice within the 32-wide k-tile

    // prefetch first W1Tt tile (thread t -> h row t, 32 bf16 = 64 B)
    uint4 wa, wb, wc, wd;
    {
        const uint4* ws = (const uint4*)(W1Tt + t * 32);
        wa = ws[0]; wb = ws[1]; wc = ws[2]; wd = ws[3];
    }

    for (int kt = 0; kt < 64; ++kt) {
        // ---- generate dots A-tile: As[row=lane][cbase..cbase+8)
        const float* xj = xls + (kt * 32 + cbase) * 3;  // wave-uniform -> LDS broadcast
        u32 d0, d1, d2, d3;
        {
            float s0 = __builtin_amdgcn_sqrtf(ax * xj[0]  + ay * xj[1]  + az * xj[2]);
            float s1 = __builtin_amdgcn_sqrtf(ax * xj[3]  + ay * xj[4]  + az * xj[5]);
            float s2 = __builtin_amdgcn_sqrtf(ax * xj[6]  + ay * xj[7]  + az * xj[8]);
            float s3 = __builtin_amdgcn_sqrtf(ax * xj[9]  + ay * xj[10] + az * xj[11]);
            float s4 = __builtin_amdgcn_sqrtf(ax * xj[12] + ay * xj[13] + az * xj[14]);
            float s5 = __builtin_amdgcn_sqrtf(ax * xj[15] + ay * xj[16] + az * xj[17]);
            float s6 = __builtin_amdgcn_sqrtf(ax * xj[18] + ay * xj[19] + az * xj[20]);
            float s7 = __builtin_amdgcn_sqrtf(ax * xj[21] + ay * xj[22] + az * xj[23]);
            d0 = pack2bf(s0, s1); d1 = pack2bf(s2, s3);
            d2 = pack2bf(s4, s5); d3 = pack2bf(s6, s7);
        }
        uint4 dv; dv.x = d0; dv.y = d1; dv.z = d2; dv.w = d3;
        *(uint4*)&As[lane][cbase] = dv;
        // ---- write prefetched W1 tile to LDS
        *(uint4*)&Bs[t][0]  = wa;
        *(uint4*)&Bs[t][8]  = wb;
        *(uint4*)&Bs[t][16] = wc;
        *(uint4*)&Bs[t][24] = wd;
        __syncthreads();
        // ---- prefetch next W1Tt tile (in flight during MFMA)
        if (kt < 63) {
            const uint4* ws = (const uint4*)(W1Tt + (kt + 1) * 8192 + t * 32);
            wa = ws[0]; wb = ws[1]; wc = ws[2]; wd = ws[3];
        }
        // ---- MFMA: rows 0..63 (shared), cols wv*64..+64
        short8 af[4], bfr[4];
#pragma unroll
        for (int i = 0; i < 4; ++i) af[i] = *(const short8*)&As[i * 16 + lr][lq * 8];
#pragma unroll
        for (int j = 0; j < 4; ++j) bfr[j] = *(const short8*)&Bs[wv * 64 + j * 16 + lr][lq * 8];
#pragma unroll
        for (int i = 0; i < 4; ++i)
#pragma unroll
            for (int j = 0; j < 4; ++j)
                acc[i][j] = mfma16(af[i], bfr[j], acc[i][j]);
        __syncthreads();
    }

    // epilogue: add small features, LeakyReLU, store bf16
#pragma unroll
    for (int i = 0; i < 4; ++i) {
#pragma unroll
        for (int r = 0; r < 4; ++r) {
            int row = i * 16 + lq * 4 + r;
            float nrm = rowsml[row][0];
            float p0 = rowsml[row][1], p1 = rowsml[row][2];
            float p2 = rowsml[row][3], p3 = rowsml[row][4];
            u16* orow = h1 + (b * 2048 + i0 + row) * 256;
#pragma unroll
            for (int j = 0; j < 4; ++j) {
                int col = wv * 64 + j * 16 + lr;
                float v = acc[i][j][r] + colsml[col][0] + nrm * colsml[col][1] +
                          p0 * colsml[col][2] + p1 * colsml[col][3] +
                          p2 * colsml[col][4] + p3 * colsml[col][5];
                v = v > 0.f ? v : 0.01f * v;
                orow[col] = f2bf(v);
            }
        }
    }
}

// ---- kernel 2: h2 = lrelu(h1 @ W2 + b2)
__global__ __launch_bounds__(256, 2) void k_h2(
    const u16* __restrict__ h1, const u16* __restrict__ W2T,
    const float* __restrict__ b2, u16* __restrict__ h2) {
    __shared__ u16 As[128][40];
    __shared__ u16 Bs[128][40];
    __shared__ float colb[128];
    const int t = threadIdx.x;
    const int n0 = blockIdx.x * 128;
    const int m0 = blockIdx.y * 128;
    const int lane = t & 63, wv = t >> 6;
    const int mb = (wv >> 1) * 64, nb = (wv & 1) * 64;
    const int lr = lane & 15, lq = lane >> 4;

    if (t < 128) colb[t] = b2[n0 + t];

    floatx4 acc[4][4];
    const floatx4 zero = {0.f, 0.f, 0.f, 0.f};
#pragma unroll
    for (int i = 0; i < 4; ++i)
#pragma unroll
        for (int j = 0; j < 4; ++j) acc[i][j] = zero;

    for (int kt = 0; kt < 8; ++kt) {
        stage_tile(h1 + m0 * 256 + kt * 32, 256, As, t);
        stage_tile(W2T + n0 * 256 + kt * 32, 256, Bs, t);
        __syncthreads();
        mfma_tile(As, Bs, acc, mb, nb, lr, lq);
        __syncthreads();
    }
#pragma unroll
    for (int i = 0; i < 4; ++i) {
#pragma unroll
        for (int r = 0; r < 4; ++r) {
            int row = mb + i * 16 + lq * 4 + r;
            u16* orow = h2 + (m0 + row) * 256 + n0;
#pragma unroll
            for (int j = 0; j < 4; ++j) {
                int col = nb + j * 16 + lr;
                float v = acc[i][j][r] + colb[col];
                v = v > 0.f ? v : 0.01f * v;
                orow[col] = f2bf(v);
            }
        }
    }
}

// ---- kernel 3: fk = h2 @ W3 + b3, fused reduce accum[b,o,d] += sum_i fk*x
__global__ __launch_bounds__(256, 2) void k_out(
    const u16* __restrict__ h2, const u16* __restrict__ W3T,
    const float* __restrict__ b3, const float* __restrict__ x,
    float* __restrict__ accum) {
    __shared__ u16 As[128][40];
    __shared__ u16 Bs[128][40];
    __shared__ float colb[128];
    __shared__ float xs[128][4];
    __shared__ float red[128][4];
    const int t = threadIdx.x;
    const int m0 = blockIdx.x * 128;
    const int b = m0 >> 11;
    const int i0 = m0 & 2047;
    const int lane = t & 63, wv = t >> 6;
    const int mb = (wv >> 1) * 64, nb = (wv & 1) * 64;
    const int lr = lane & 15, lq = lane >> 4;

    if (t < 128) {
        colb[t] = b3[t];
        const float* xp = x + (b * 2048 + i0 + t) * 3;
        xs[t][0] = xp[0]; xs[t][1] = xp[1]; xs[t][2] = xp[2];
        red[t][0] = 0.f; red[t][1] = 0.f; red[t][2] = 0.f; red[t][3] = 0.f;
    }

    floatx4 acc[4][4];
    const floatx4 zero = {0.f, 0.f, 0.f, 0.f};
#pragma unroll
    for (int i = 0; i < 4; ++i)
#pragma unroll
        for (int j = 0; j < 4; ++j) acc[i][j] = zero;

    for (int kt = 0; kt < 8; ++kt) {
        stage_tile(h2 + m0 * 256 + kt * 32, 256, As, t);
        stage_tile(W3T + kt * 32, 256, Bs, t);
        __syncthreads();
        mfma_tile(As, Bs, acc, mb, nb, lr, lq);
        __syncthreads();
    }

    float s[4][3];
#pragma unroll
    for (int j = 0; j < 4; ++j) { s[j][0] = 0.f; s[j][1] = 0.f; s[j][2] = 0.f; }
#pragma unroll
    for (int i = 0; i < 4; ++i) {
#pragma unroll
        for (int r = 0; r < 4; ++r) {
            int row = mb + i * 16 + lq * 4 + r;
            float x0 = xs[row][0], x1 = xs[row][1], x2 = xs[row][2];
#pragma unroll
            for (int j = 0; j < 4; ++j) {
                int col = nb + j * 16 + lr;
                float fk = acc[i][j][r] + colb[col];
                s[j][0] += fk * x0; s[j][1] += fk * x1; s[j][2] += fk * x2;
            }
        }
    }
#pragma unroll
    for (int j = 0; j < 4; ++j)
#pragma unroll
        for (int d = 0; d < 3; ++d) {
            float v = s[j][d];
            v += __shfl_xor(v, 16);
            v += __shfl_xor(v, 32);
            if (lane < 16) atomicAdd(&red[nb + j * 16 + lane][d], v);
        }
    __syncthreads();
    if (t < 128) {
#pragma unroll
        for (int d = 0; d < 3; ++d)
            atomicAdd(&accum[(b * 128 + t) * 3 + d], red[t][d]);
    }
}

__global__ void k_fin(const float* __restrict__ accum, float* __restrict__ out) {
    int idx = blockIdx.x * 256 + threadIdx.x;
    if (idx < 6144) out[idx] = accum[idx] * (1.0f / 2048.0f);
}

extern "C" void kernel_launch(void* const* d_in, const int* in_sizes, int n_in,
                              void* d_out, int out_size, void* d_ws, size_t ws_size,
                              hipStream_t stream) {
    const float* x     = (const float*)d_in[0];
    const float* u     = (const float*)d_in[1];
    const float* basis = (const float*)d_in[2];
    const float* W1    = (const float*)d_in[3];
    const float* b1    = (const float*)d_in[4];
    const float* W2    = (const float*)d_in[5];
    const float* b2    = (const float*)d_in[6];
    const float* W3    = (const float*)d_in[7];
    const float* b3    = (const float*)d_in[8];
    float* out = (float*)d_out;

    char* ws = (char*)d_ws;
    u16*  W1Tt  = (u16*)ws;                       // 1,048,576 B  [64][256][32]
    u16*  W2T   = (u16*)(ws + 1048576);           //   131,072 B
    u16*  W3T   = (u16*)(ws + 1179648);           //    65,536 B
    u16*  h1    = (u16*)(ws + 1245184);           // 16,777,216 B
    u16*  h2    = (u16*)(ws + 18022400);          // 16,777,216 B
    float* accum = (float*)(ws + 34799616);       //    24,576 B

    hipMemsetAsync(accum, 0, 24576, stream);
    k_prep<<<2432, 256, 0, stream>>>(W1, W2, W3, W1Tt, W2T, W3T);
    k_h1<<<dim3(32, 16), 256, 0, stream>>>(x, u, basis, W1, b1, W1Tt, h1);
    k_h2<<<dim3(2, 256), 256, 0, stream>>>(h1, W2T, b2, h2);
    k_out<<<256, 256, 0, stream>>>(h2, W3T, b3, x, accum);
    k_fin<<<24, 256, 0, stream>>>(accum, out);
}

// Round 4
// 145.007 us; speedup vs baseline: 1.6240x; 1.1307x over previous
//
#include <hip/hip_runtime.h>

typedef unsigned short u16;
typedef unsigned int   u32;

typedef __attribute__((ext_vector_type(8))) short short8;
typedef __attribute__((ext_vector_type(4))) float floatx4;

// ---- f32 -> bf16 (RNE) ----
__device__ __forceinline__ u16 f2bf(float f) {
    u32 u = __float_as_uint(f);
    u = u + 0x7fffu + ((u >> 16) & 1u);
    return (u16)(u >> 16);
}

// pack two f32 -> two bf16 (round-to-nearest-away) in one v_perm
__device__ __forceinline__ u32 pack2bf(float s0, float s1) {
    u32 a = __float_as_uint(s0) + 0x8000u;
    u32 b = __float_as_uint(s1) + 0x8000u;
    return __builtin_amdgcn_perm(b, a, 0x07060302u);  // {b.hi16, a.hi16}
}

__device__ __forceinline__ floatx4 mfma16(short8 a, short8 b, floatx4 c) {
    return __builtin_amdgcn_mfma_f32_16x16x32_bf16(a, b, c, 0, 0, 0);
}

// ---- prep: build per-thread B-fragment stream for k_h1, plus W2T/W3T.
// W1frag[kt*8192 + t*32 + jj*8 + ji] = bf16(W1[(7 + kt*32 + lq*8 + ji)*256 + n])
//   where lane=t&63, wv=t>>6, lr=lane&15, lq=lane>>4, n=wv*64+jj*16+lr.
__global__ void k_prep(const float* __restrict__ W1, const float* __restrict__ W2,
                       const float* __restrict__ W3, u16* __restrict__ W1frag,
                       u16* __restrict__ W2T, u16* __restrict__ W3T) {
    int idx = blockIdx.x * 256 + threadIdx.x;
    if (idx < 524288) {
        int kt = idx >> 13, r = idx & 8191;
        int t = r >> 5, jj = (r >> 3) & 3, ji = r & 7;
        int lane = t & 63, wv = t >> 6, lr = lane & 15, lq = lane >> 4;
        int n = wv * 64 + jj * 16 + lr;
        int k = kt * 32 + lq * 8 + ji;
        W1frag[idx] = f2bf(W1[(7 + k) * 256 + n]);
    } else if (idx < 589824) {
        int i = idx - 524288;
        int n = i >> 8, k = i & 255;
        W2T[i] = f2bf(W2[k * 256 + n]);
    } else if (idx < 622592) {
        int i = idx - 589824;
        int n = i >> 8, k = i & 255;
        W3T[i] = f2bf(W3[k * 128 + n]);
    }
}

// ---- kernel 1: h1 = lrelu( [u,norm,proj,dots] @ W1 + b1 )
// M=64 x N=256(full H) per block. Dots gen: lane=row, wave=8-col slice (xj broadcast).
// B-frags direct global->reg (no LDS); As double-buffered -> 1 barrier/kt.
__global__ __launch_bounds__(256, 2) void k_h1(
    const float* __restrict__ x, const float* __restrict__ u,
    const float* __restrict__ basis, const float* __restrict__ W1,
    const float* __restrict__ b1, const u16* __restrict__ W1frag,
    u16* __restrict__ h1) {
    __shared__ float4 xls4[1536];     // 24 KB: all 2048 points of batch b
    __shared__ u16 As[2][64][40];     // 10 KB double-buffered dots tile
    __shared__ float rowsml[64][6];
    __shared__ float colsml[256][6];

    const int t = threadIdx.x;
    const int b = blockIdx.y;
    const int i0 = blockIdx.x * 64;
    const int lane = t & 63, wv = t >> 6;
    const int lr = lane & 15, lq = lane >> 4;
    float* xls = (float*)xls4;

    {
        const float4* src = (const float4*)(x + b * 6144);
#pragma unroll
        for (int i = 0; i < 6; ++i) xls4[t + i * 256] = src[t + i * 256];
    }
    {
        int c = t;
        float u0 = u[b * 2 + 0], u1 = u[b * 2 + 1];
        colsml[c][0] = b1[c] + u0 * W1[c] + u1 * W1[256 + c];
        colsml[c][1] = W1[512 + c];
        colsml[c][2] = W1[768 + c];
        colsml[c][3] = W1[1024 + c];
        colsml[c][4] = W1[1280 + c];
        colsml[c][5] = W1[1536 + c];
    }
    __syncthreads();
    if (t < 64) {
        float xx = xls[(i0 + t) * 3], xy = xls[(i0 + t) * 3 + 1], xz = xls[(i0 + t) * 3 + 2];
        rowsml[t][0] = sqrtf(xx * xx + xy * xy + xz * xz);
#pragma unroll
        for (int p = 0; p < 4; ++p) {
            const float* bp = basis + (b * 4 + p) * 3;
            rowsml[t][1 + p] = xx * bp[0] + xy * bp[1] + xz * bp[2];
        }
    }
    const float ax = xls[(i0 + lane) * 3];
    const float ay = xls[(i0 + lane) * 3 + 1];
    const float az = xls[(i0 + lane) * 3 + 2];
    const int cbase = wv * 8;
    const u16* wf = W1frag + t * 32;

    // generate 8 dots for k-tile kt, store into As[buf]
    auto gen_store = [&](int kt, int buf) {
        int q = kt * 24 + wv * 6;  // wave-uniform -> LDS broadcast reads
        float4 q0 = xls4[q], q1 = xls4[q + 1], q2 = xls4[q + 2];
        float4 q3 = xls4[q + 3], q4 = xls4[q + 4], q5 = xls4[q + 5];
        float s0 = __builtin_amdgcn_sqrtf(ax * q0.x + ay * q0.y + az * q0.z);
        float s1 = __builtin_amdgcn_sqrtf(ax * q0.w + ay * q1.x + az * q1.y);
        float s2 = __builtin_amdgcn_sqrtf(ax * q1.z + ay * q1.w + az * q2.x);
        float s3 = __builtin_amdgcn_sqrtf(ax * q2.y + ay * q2.z + az * q2.w);
        float s4 = __builtin_amdgcn_sqrtf(ax * q3.x + ay * q3.y + az * q3.z);
        float s5 = __builtin_amdgcn_sqrtf(ax * q3.w + ay * q4.x + az * q4.y);
        float s6 = __builtin_amdgcn_sqrtf(ax * q4.z + ay * q4.w + az * q5.x);
        float s7 = __builtin_amdgcn_sqrtf(ax * q5.y + ay * q5.z + az * q5.w);
        uint4 dv;
        dv.x = pack2bf(s0, s1); dv.y = pack2bf(s2, s3);
        dv.z = pack2bf(s4, s5); dv.w = pack2bf(s6, s7);
        *(uint4*)&As[buf][lane][cbase] = dv;
    };

    floatx4 acc[4][4];
    const floatx4 zero = {0.f, 0.f, 0.f, 0.f};
#pragma unroll
    for (int i = 0; i < 4; ++i)
#pragma unroll
        for (int j = 0; j < 4; ++j) acc[i][j] = zero;

    short8 acur[4], bcur[4], bnxt[4];
    gen_store(0, 0);
#pragma unroll
    for (int j = 0; j < 4; ++j) bcur[j] = *(const short8*)(wf + j * 8);
    __syncthreads();
#pragma unroll
    for (int i = 0; i < 4; ++i) acur[i] = *(const short8*)&As[0][i * 16 + lr][lq * 8];

#pragma unroll 2
    for (int kt = 0; kt < 64; ++kt) {
        if (kt < 63) {
            const u16* wn = wf + (kt + 1) * 8192;  // coalesced 64B/thread, L2/L3-hot
#pragma unroll
            for (int j = 0; j < 4; ++j) bnxt[j] = *(const short8*)(wn + j * 8);
            gen_store(kt + 1, (kt + 1) & 1);
        }
#pragma unroll
        for (int i = 0; i < 4; ++i)
#pragma unroll
            for (int j = 0; j < 4; ++j)
                acc[i][j] = mfma16(acur[i], bcur[j], acc[i][j]);
        __syncthreads();
        if (kt < 63) {
#pragma unroll
            for (int i = 0; i < 4; ++i)
                acur[i] = *(const short8*)&As[(kt + 1) & 1][i * 16 + lr][lq * 8];
#pragma unroll
            for (int j = 0; j < 4; ++j) bcur[j] = bnxt[j];
        }
    }

    // epilogue: small features + bias, LeakyReLU, store bf16
#pragma unroll
    for (int i = 0; i < 4; ++i) {
#pragma unroll
        for (int r = 0; r < 4; ++r) {
            int row = i * 16 + lq * 4 + r;
            float nrm = rowsml[row][0];
            float p0 = rowsml[row][1], p1 = rowsml[row][2];
            float p2 = rowsml[row][3], p3 = rowsml[row][4];
            u16* orow = h1 + (b * 2048 + i0 + row) * 256;
#pragma unroll
            for (int j = 0; j < 4; ++j) {
                int col = wv * 64 + j * 16 + lr;
                float v = acc[i][j][r] + colsml[col][0] + nrm * colsml[col][1] +
                          p0 * colsml[col][2] + p1 * colsml[col][3] +
                          p2 * colsml[col][4] + p3 * colsml[col][5];
                v = v > 0.f ? v : 0.01f * v;
                orow[col] = f2bf(v);
            }
        }
    }
}

// ---- fused tail: h2 = lrelu(h1@W2+b2) (kept in LDS), fk = h2@W3+b3,
// accum[b,o,d] += sum_i fk*x. M=64 rows per block, 512 blocks.
__global__ __launch_bounds__(256, 2) void k_tail(
    const u16* __restrict__ h1, const u16* __restrict__ W2T,
    const float* __restrict__ b2, const u16* __restrict__ W3T,
    const float* __restrict__ b3, const float* __restrict__ x,
    float* __restrict__ accum) {
    __shared__ u16 As[64][40];      // 5 KB
    __shared__ u16 Bs[256][40];     // 20 KB (phase2 aliases Ws[128][40] here)
    __shared__ u16 h2s[64][264];    // 33.8 KB
    __shared__ float colb2[256];
    __shared__ float colb3[128];
    __shared__ float xs[64][4];
    __shared__ float red[128][4];

    const int t = threadIdx.x;
    const int m0 = blockIdx.x * 64;
    const int b = m0 >> 11, i0 = m0 & 2047;
    const int lane = t & 63, wv = t >> 6;
    const int lr = lane & 15, lq = lane >> 4;

    colb2[t] = b2[t];
    if (t < 128) colb3[t] = b3[t];
    if (t < 64) {
        const float* xp = x + (b * 2048 + i0 + t) * 3;
        xs[t][0] = xp[0]; xs[t][1] = xp[1]; xs[t][2] = xp[2];
    }

    // ---- phase 1: h2 tile
    floatx4 acc[4][4];
    const floatx4 zero = {0.f, 0.f, 0.f, 0.f};
#pragma unroll
    for (int i = 0; i < 4; ++i)
#pragma unroll
        for (int j = 0; j < 4; ++j) acc[i][j] = zero;

    const int ar = t >> 2, ac = (t & 3) * 8;
    for (int kt = 0; kt < 8; ++kt) {
        *(uint4*)&As[ar][ac] = *(const uint4*)(h1 + (m0 + ar) * 256 + kt * 32 + ac);
        const u16* wsrc = W2T + t * 256 + kt * 32;
        *(uint4*)&Bs[t][0]  = *(const uint4*)(wsrc);
        *(uint4*)&Bs[t][8]  = *(const uint4*)(wsrc + 8);
        *(uint4*)&Bs[t][16] = *(const uint4*)(wsrc + 16);
        *(uint4*)&Bs[t][24] = *(const uint4*)(wsrc + 24);
        __syncthreads();
        short8 af[4], bf[4];
#pragma unroll
        for (int i = 0; i < 4; ++i) af[i] = *(const short8*)&As[i * 16 + lr][lq * 8];
#pragma unroll
        for (int j = 0; j < 4; ++j) bf[j] = *(const short8*)&Bs[wv * 64 + j * 16 + lr][lq * 8];
#pragma unroll
        for (int i = 0; i < 4; ++i)
#pragma unroll
            for (int j = 0; j < 4; ++j) acc[i][j] = mfma16(af[i], bf[j], acc[i][j]);
        __syncthreads();
    }
#pragma unroll
    for (int i = 0; i < 4; ++i)
#pragma unroll
        for (int r = 0; r < 4; ++r) {
            int row = i * 16 + lq * 4 + r;
#pragma unroll
            for (int j = 0; j < 4; ++j) {
                int col = wv * 64 + j * 16 + lr;
                float v = acc[i][j][r] + colb2[col];
                v = v > 0.f ? v : 0.01f * v;
                h2s[row][col] = f2bf(v);
            }
        }
    __syncthreads();

    // ---- phase 2: fk = h2s @ W3 + b3, fused x-reduce
    floatx4 acc2[4][2];
#pragma unroll
    for (int i = 0; i < 4; ++i)
#pragma unroll
        for (int j = 0; j < 2; ++j) acc2[i][j] = zero;

    u16 (*Ws)[40] = (u16(*)[40])Bs;
    const int wr = t & 127, wseg = (t >> 7) * 16;
    for (int kt = 0; kt < 8; ++kt) {
        const u16* w3src = W3T + wr * 256 + kt * 32 + wseg;
        *(uint4*)&Ws[wr][wseg]     = *(const uint4*)(w3src);
        *(uint4*)&Ws[wr][wseg + 8] = *(const uint4*)(w3src + 8);
        __syncthreads();
        short8 af[4], bf[2];
#pragma unroll
        for (int i = 0; i < 4; ++i) af[i] = *(const short8*)&h2s[i * 16 + lr][kt * 32 + lq * 8];
#pragma unroll
        for (int j = 0; j < 2; ++j) bf[j] = *(const short8*)&Ws[wv * 32 + j * 16 + lr][lq * 8];
#pragma unroll
        for (int i = 0; i < 4; ++i)
#pragma unroll
            for (int j = 0; j < 2; ++j) acc2[i][j] = mfma16(af[i], bf[j], acc2[i][j]);
        __syncthreads();
    }

    float s[2][3];
#pragma unroll
    for (int j = 0; j < 2; ++j) { s[j][0] = 0.f; s[j][1] = 0.f; s[j][2] = 0.f; }
#pragma unroll
    for (int i = 0; i < 4; ++i)
#pragma unroll
        for (int r = 0; r < 4; ++r) {
            int row = i * 16 + lq * 4 + r;
            float x0 = xs[row][0], x1 = xs[row][1], x2 = xs[row][2];
#pragma unroll
            for (int j = 0; j < 2; ++j) {
                int col = wv * 32 + j * 16 + lr;
                float fk = acc2[i][j][r] + colb3[col];
                s[j][0] += fk * x0; s[j][1] += fk * x1; s[j][2] += fk * x2;
            }
        }
#pragma unroll
    for (int j = 0; j < 2; ++j)
#pragma unroll
        for (int d = 0; d < 3; ++d) {
            float v = s[j][d];
            v += __shfl_xor(v, 16);
            v += __shfl_xor(v, 32);
            if (lane < 16) red[wv * 32 + j * 16 + lane][d] = v;  // wave-exclusive cols
        }
    __syncthreads();
    if (t < 128) {
#pragma unroll
        for (int d = 0; d < 3; ++d)
            atomicAdd(&accum[(b * 128 + t) * 3 + d], red[t][d]);
    }
}

__global__ void k_fin(const float* __restrict__ accum, float* __restrict__ out) {
    int idx = blockIdx.x * 256 + threadIdx.x;
    if (idx < 6144) out[idx] = accum[idx] * (1.0f / 2048.0f);
}

extern "C" void kernel_launch(void* const* d_in, const int* in_sizes, int n_in,
                              void* d_out, int out_size, void* d_ws, size_t ws_size,
                              hipStream_t stream) {
    const float* x     = (const float*)d_in[0];
    const float* u     = (const float*)d_in[1];
    const float* basis = (const float*)d_in[2];
    const float* W1    = (const float*)d_in[3];
    const float* b1    = (const float*)d_in[4];
    const float* W2    = (const float*)d_in[5];
    const float* b2    = (const float*)d_in[6];
    const float* W3    = (const float*)d_in[7];
    const float* b3    = (const float*)d_in[8];
    float* out = (float*)d_out;

    char* ws = (char*)d_ws;
    u16*  W1frag = (u16*)ws;                      // 1,048,576 B  [64][256][32]
    u16*  W2T    = (u16*)(ws + 1048576);          //   131,072 B
    u16*  W3T    = (u16*)(ws + 1179648);          //    65,536 B
    u16*  h1     = (u16*)(ws + 1245184);          // 16,777,216 B
    float* accum = (float*)(ws + 18022400);       //    24,576 B

    hipMemsetAsync(accum, 0, 24576, stream);
    k_prep<<<2432, 256, 0, stream>>>(W1, W2, W3, W1frag, W2T, W3T);
    k_h1<<<dim3(32, 16), 256, 0, stream>>>(x, u, basis, W1, b1, W1frag, h1);
    k_tail<<<512, 256, 0, stream>>>(h1, W2T, b2, W3T, b3, x, accum);
    k_fin<<<24, 256, 0, stream>>>(accum, out);
}

// Round 5
// 143.606 us; speedup vs baseline: 1.6399x; 1.0098x over previous
//
#include <hip/hip_runtime.h>

typedef unsigned short u16;
typedef unsigned int   u32;

typedef __attribute__((ext_vector_type(8))) short short8;
typedef __attribute__((ext_vector_type(4))) float floatx4;
typedef __attribute__((ext_vector_type(2))) float v2f;

// ---- f32 -> bf16 (RNE) ----
__device__ __forceinline__ u16 f2bf(float f) {
    u32 u = __float_as_uint(f);
    u = u + 0x7fffu + ((u >> 16) & 1u);
    return (u16)(u >> 16);
}

// pack two f32 -> two bf16 (round-to-nearest-away) in one v_perm
__device__ __forceinline__ u32 pack2bf(float s0, float s1) {
    u32 a = __float_as_uint(s0) + 0x8000u;
    u32 b = __float_as_uint(s1) + 0x8000u;
    return __builtin_amdgcn_perm(b, a, 0x07060302u);  // {b.hi16, a.hi16}
}

__device__ __forceinline__ floatx4 mfma16(short8 a, short8 b, floatx4 c) {
    return __builtin_amdgcn_mfma_f32_16x16x32_bf16(a, b, c, 0, 0, 0);
}

// ---- prep: build per-thread B-fragment streams.
// W1frag (k_h1, 512-thr): [kt*8192 + t*16 + j*8 + ji] = bf16(W1[(7+kt*32+lq*8+ji)*256 + w*32+j*16+lr])
// W2frag (k_tail p1, 256-thr): [kt*8192 + t*32 + jj*8 + ji] = bf16(W2[(kt*32+lq*8+ji)*256 + wv*64+jj*16+lr])
// W3frag (k_tail p2, 256-thr): [kt*4096 + t*16 + j*8 + ji]  = bf16(W3[(kt*32+lq*8+ji)*128 + wv*32+j*16+lr])
__global__ void k_prep(const float* __restrict__ W1, const float* __restrict__ W2,
                       const float* __restrict__ W3, u16* __restrict__ W1frag,
                       u16* __restrict__ W2frag, u16* __restrict__ W3frag) {
    int idx = blockIdx.x * 256 + threadIdx.x;
    if (idx < 524288) {
        int kt = idx >> 13, r = idx & 8191;
        int t = r >> 4, j = (r >> 3) & 1, ji = r & 7;
        int lane = t & 63, w = t >> 6, lr = lane & 15, lq = lane >> 4;
        W1frag[idx] = f2bf(W1[(7 + kt * 32 + lq * 8 + ji) * 256 + w * 32 + j * 16 + lr]);
    } else if (idx < 589824) {
        int i = idx - 524288;
        int kt = i >> 13, r = i & 8191;
        int t = r >> 5, jj = (r >> 3) & 3, ji = r & 7;
        int lane = t & 63, wv = t >> 6, lr = lane & 15, lq = lane >> 4;
        W2frag[i] = f2bf(W2[(kt * 32 + lq * 8 + ji) * 256 + wv * 64 + jj * 16 + lr]);
    } else if (idx < 622592) {
        int i = idx - 589824;
        int kt = i >> 12, r = i & 4095;
        int t = r >> 4, j = (r >> 3) & 1, ji = r & 7;
        int lane = t & 63, wv = t >> 6, lr = lane & 15, lq = lane >> 4;
        W3frag[i] = f2bf(W3[(kt * 32 + lq * 8 + ji) * 128 + wv * 32 + j * 16 + lr]);
    }
}

// ---- kernel 1: h1 = lrelu( [u,norm,proj,dots] @ W1 + b1 )
// 512 threads (8 waves), M=64 x N=256 per block; wave w owns cols w*32..+32.
// Gen: lane=row, wave gens 4 cols (SoA xls -> packed-fp32 math, broadcast reads).
__global__ __launch_bounds__(512, 4) void k_h1(
    const float* __restrict__ x, const float* __restrict__ u,
    const float* __restrict__ basis, const float* __restrict__ W1,
    const float* __restrict__ b1, const u16* __restrict__ W1frag,
    u16* __restrict__ h1) {
    __shared__ float xls[6144];       // SoA: X[0..2048) Y[2048..4096) Z[4096..6144)
    __shared__ u16 As[2][64][40];     // 10 KB double-buffered dots tile
    __shared__ float rowsml[64][6];
    __shared__ float colsml[256][6];

    const int t = threadIdx.x;
    const int b = blockIdx.y;
    const int i0 = blockIdx.x * 64;
    const int lane = t & 63, w = t >> 6;
    const int lr = lane & 15, lq = lane >> 4;

    // build SoA copy of x[b] (coalesced read, scalar LDS scatter; one-time)
    {
        const float4* src = (const float4*)(x + b * 6144);
#pragma unroll
        for (int kk = 0; kk < 3; ++kk) {
            int q = t + kk * 512;
            float4 v = src[q];
            float vv[4] = {v.x, v.y, v.z, v.w};
            int e = q * 4;
#pragma unroll
            for (int cc = 0; cc < 4; ++cc) {
                int ee = e + cc;
                xls[(ee % 3) * 2048 + ee / 3] = vv[cc];
            }
        }
    }
    if (t < 256) {
        int c = t;
        float u0 = u[b * 2 + 0], u1 = u[b * 2 + 1];
        colsml[c][0] = b1[c] + u0 * W1[c] + u1 * W1[256 + c];
        colsml[c][1] = W1[512 + c];
        colsml[c][2] = W1[768 + c];
        colsml[c][3] = W1[1024 + c];
        colsml[c][4] = W1[1280 + c];
        colsml[c][5] = W1[1536 + c];
    }
    __syncthreads();
    if (t < 64) {
        float xx = xls[i0 + t], xy = xls[2048 + i0 + t], xz = xls[4096 + i0 + t];
        rowsml[t][0] = sqrtf(xx * xx + xy * xy + xz * xz);
#pragma unroll
        for (int p = 0; p < 4; ++p) {
            const float* bp = basis + (b * 4 + p) * 3;
            rowsml[t][1 + p] = xx * bp[0] + xy * bp[1] + xz * bp[2];
        }
    }
    const float ax = xls[i0 + lane];
    const float ay = xls[2048 + i0 + lane];
    const float az = xls[4096 + i0 + lane];
    const u16* wf = W1frag + t * 16;
    const float4* X4 = (const float4*)xls;  // [0..512) X, [512..1024) Y, [1024..1536) Z

    // generate 4 dots (cols kt*32 + w*4 ..+3) for k-tile kt into As[buf]
    auto gen_store = [&](int kt, int buf) {
        int q = kt * 8 + w;                       // wave-uniform -> LDS broadcast
        float4 xv = X4[q], yv = X4[512 + q], zv = X4[1024 + q];
        v2f xlo = {xv.x, xv.y}, xhi = {xv.z, xv.w};
        v2f ylo = {yv.x, yv.y}, yhi = {yv.z, yv.w};
        v2f zlo = {zv.x, zv.y}, zhi = {zv.z, zv.w};
        v2f dlo = xlo * ax, dhi = xhi * ax;       // packed fp32
        dlo += ylo * ay; dhi += yhi * ay;
        dlo += zlo * az; dhi += zhi * az;
        float s0 = __builtin_amdgcn_sqrtf(dlo.x);
        float s1 = __builtin_amdgcn_sqrtf(dlo.y);
        float s2 = __builtin_amdgcn_sqrtf(dhi.x);
        float s3 = __builtin_amdgcn_sqrtf(dhi.y);
        uint2 dv; dv.x = pack2bf(s0, s1); dv.y = pack2bf(s2, s3);
        *(uint2*)&As[buf][lane][w * 4] = dv;
    };

    floatx4 acc[4][2];
    const floatx4 zero = {0.f, 0.f, 0.f, 0.f};
#pragma unroll
    for (int i = 0; i < 4; ++i)
#pragma unroll
        for (int j = 0; j < 2; ++j) acc[i][j] = zero;

    short8 acur[4], bcur[2], bnxt[2];
    gen_store(0, 0);
#pragma unroll
    for (int j = 0; j < 2; ++j) bcur[j] = *(const short8*)(wf + j * 8);
    __syncthreads();
#pragma unroll
    for (int i = 0; i < 4; ++i) acur[i] = *(const short8*)&As[0][i * 16 + lr][lq * 8];

#pragma unroll 2
    for (int kt = 0; kt < 64; ++kt) {
        if (kt < 63) {
            const u16* wn = wf + (kt + 1) * 8192;  // 32B/thread, L2-hot
#pragma unroll
            for (int j = 0; j < 2; ++j) bnxt[j] = *(const short8*)(wn + j * 8);
            gen_store(kt + 1, (kt + 1) & 1);
        }
#pragma unroll
        for (int i = 0; i < 4; ++i)
#pragma unroll
            for (int j = 0; j < 2; ++j)
                acc[i][j] = mfma16(acur[i], bcur[j], acc[i][j]);
        __syncthreads();
        if (kt < 63) {
#pragma unroll
            for (int i = 0; i < 4; ++i)
                acur[i] = *(const short8*)&As[(kt + 1) & 1][i * 16 + lr][lq * 8];
#pragma unroll
            for (int j = 0; j < 2; ++j) bcur[j] = bnxt[j];
        }
    }

    // epilogue: small features + bias, LeakyReLU, store bf16
    const int c0 = w * 32 + lr, c1 = c0 + 16;
    float c0v[6], c1v[6];
#pragma unroll
    for (int q = 0; q < 6; ++q) { c0v[q] = colsml[c0][q]; c1v[q] = colsml[c1][q]; }
#pragma unroll
    for (int i = 0; i < 4; ++i) {
#pragma unroll
        for (int r = 0; r < 4; ++r) {
            int row = i * 16 + lq * 4 + r;
            float nrm = rowsml[row][0];
            float p0 = rowsml[row][1], p1 = rowsml[row][2];
            float p2 = rowsml[row][3], p3 = rowsml[row][4];
            u16* orow = h1 + (b * 2048 + i0 + row) * 256;
            float v0 = acc[i][0][r] + c0v[0] + nrm * c0v[1] +
                       p0 * c0v[2] + p1 * c0v[3] + p2 * c0v[4] + p3 * c0v[5];
            v0 = v0 > 0.f ? v0 : 0.01f * v0;
            orow[c0] = f2bf(v0);
            float v1 = acc[i][1][r] + c1v[0] + nrm * c1v[1] +
                       p0 * c1v[2] + p1 * c1v[3] + p2 * c1v[4] + p3 * c1v[5];
            v1 = v1 > 0.f ? v1 : 0.01f * v1;
            orow[c1] = f2bf(v1);
        }
    }
}

// ---- fused tail: h2 = lrelu(h1@W2+b2) (regs->LDS), fk = h2@W3+b3, x-reduce.
// Phase 1 is barrier-free: A-frags direct from global h1, B-frags from W2frag stream.
__global__ __launch_bounds__(256, 2) void k_tail(
    const u16* __restrict__ h1, const u16* __restrict__ W2frag,
    const float* __restrict__ b2, const u16* __restrict__ W3frag,
    const float* __restrict__ b3, const float* __restrict__ x,
    float* __restrict__ accum) {
    __shared__ u16 h2s[64][264];    // 33.8 KB
    __shared__ float colb2[256];
    __shared__ float colb3[128];
    __shared__ float xs[64][4];
    __shared__ float red[128][4];

    const int t = threadIdx.x;
    const int m0 = blockIdx.x * 64;
    const int b = m0 >> 11, i0 = m0 & 2047;
    const int lane = t & 63, wv = t >> 6;
    const int lr = lane & 15, lq = lane >> 4;

    colb2[t] = b2[t];
    if (t < 128) colb3[t] = b3[t];
    if (t < 64) {
        const float* xp = x + (b * 2048 + i0 + t) * 3;
        xs[t][0] = xp[0]; xs[t][1] = xp[1]; xs[t][2] = xp[2];
    }

    // ---- phase 1: h2 tile (no barriers, no LDS staging)
    floatx4 acc[4][4];
    const floatx4 zero = {0.f, 0.f, 0.f, 0.f};
#pragma unroll
    for (int i = 0; i < 4; ++i)
#pragma unroll
        for (int j = 0; j < 4; ++j) acc[i][j] = zero;

    const u16* hsrc = h1 + m0 * 256 + lr * 256 + lq * 8;
    const u16* w2s = W2frag + t * 32;
#pragma unroll 2
    for (int kt = 0; kt < 8; ++kt) {
        short8 af[4], bf[4];
#pragma unroll
        for (int i = 0; i < 4; ++i)
            af[i] = *(const short8*)(hsrc + i * 4096 + kt * 32);
#pragma unroll
        for (int j = 0; j < 4; ++j)
            bf[j] = *(const short8*)(w2s + kt * 8192 + j * 8);
#pragma unroll
        for (int i = 0; i < 4; ++i)
#pragma unroll
            for (int j = 0; j < 4; ++j) acc[i][j] = mfma16(af[i], bf[j], acc[i][j]);
    }
#pragma unroll
    for (int i = 0; i < 4; ++i)
#pragma unroll
        for (int r = 0; r < 4; ++r) {
            int row = i * 16 + lq * 4 + r;
#pragma unroll
            for (int j = 0; j < 4; ++j) {
                int col = wv * 64 + j * 16 + lr;
                float v = acc[i][j][r] + colb2[col];
                v = v > 0.f ? v : 0.01f * v;
                h2s[row][col] = f2bf(v);
            }
        }
    __syncthreads();

    // ---- phase 2: fk = h2s @ W3 + b3 (B from W3frag stream), fused x-reduce
    floatx4 acc2[4][2];
#pragma unroll
    for (int i = 0; i < 4; ++i)
#pragma unroll
        for (int j = 0; j < 2; ++j) acc2[i][j] = zero;

    const u16* w3s = W3frag + t * 16;
#pragma unroll 2
    for (int kt = 0; kt < 8; ++kt) {
        short8 af[4], bf[2];
#pragma unroll
        for (int i = 0; i < 4; ++i)
            af[i] = *(const short8*)&h2s[i * 16 + lr][kt * 32 + lq * 8];
#pragma unroll
        for (int j = 0; j < 2; ++j)
            bf[j] = *(const short8*)(w3s + kt * 4096 + j * 8);
#pragma unroll
        for (int i = 0; i < 4; ++i)
#pragma unroll
            for (int j = 0; j < 2; ++j) acc2[i][j] = mfma16(af[i], bf[j], acc2[i][j]);
    }

    float s[2][3];
#pragma unroll
    for (int j = 0; j < 2; ++j) { s[j][0] = 0.f; s[j][1] = 0.f; s[j][2] = 0.f; }
#pragma unroll
    for (int i = 0; i < 4; ++i)
#pragma unroll
        for (int r = 0; r < 4; ++r) {
            int row = i * 16 + lq * 4 + r;
            float x0 = xs[row][0], x1 = xs[row][1], x2 = xs[row][2];
#pragma unroll
            for (int j = 0; j < 2; ++j) {
                int col = wv * 32 + j * 16 + lr;
                float fk = acc2[i][j][r] + colb3[col];
                s[j][0] += fk * x0; s[j][1] += fk * x1; s[j][2] += fk * x2;
            }
        }
#pragma unroll
    for (int j = 0; j < 2; ++j)
#pragma unroll
        for (int d = 0; d < 3; ++d) {
            float v = s[j][d];
            v += __shfl_xor(v, 16);
            v += __shfl_xor(v, 32);
            if (lane < 16) red[wv * 32 + j * 16 + lane][d] = v;  // wave-exclusive cols
        }
    __syncthreads();
    if (t < 128) {
#pragma unroll
        for (int d = 0; d < 3; ++d)
            atomicAdd(&accum[(b * 128 + t) * 3 + d], red[t][d]);
    }
}

__global__ void k_fin(const float* __restrict__ accum, float* __restrict__ out) {
    int idx = blockIdx.x * 256 + threadIdx.x;
    if (idx < 6144) out[idx] = accum[idx] * (1.0f / 2048.0f);
}

extern "C" void kernel_launch(void* const* d_in, const int* in_sizes, int n_in,
                              void* d_out, int out_size, void* d_ws, size_t ws_size,
                              hipStream_t stream) {
    const float* x     = (const float*)d_in[0];
    const float* u     = (const float*)d_in[1];
    const float* basis = (const float*)d_in[2];
    const float* W1    = (const float*)d_in[3];
    const float* b1    = (const float*)d_in[4];
    const float* W2    = (const float*)d_in[5];
    const float* b2    = (const float*)d_in[6];
    const float* W3    = (const float*)d_in[7];
    const float* b3    = (const float*)d_in[8];
    float* out = (float*)d_out;

    char* ws = (char*)d_ws;
    u16*  W1frag = (u16*)ws;                      // 1,048,576 B
    u16*  W2frag = (u16*)(ws + 1048576);          //   131,072 B
    u16*  W3frag = (u16*)(ws + 1179648);          //    65,536 B
    u16*  h1     = (u16*)(ws + 1245184);          // 16,777,216 B
    float* accum = (float*)(ws + 18022400);       //    24,576 B

    hipMemsetAsync(accum, 0, 24576, stream);
    k_prep<<<2432, 256, 0, stream>>>(W1, W2, W3, W1frag, W2frag, W3frag);
    k_h1<<<dim3(32, 16), 512, 0, stream>>>(x, u, basis, W1, b1, W1frag, h1);
    k_tail<<<512, 256, 0, stream>>>(h1, W2frag, b2, W3frag, b3, x, accum);
    k_fin<<<24, 256, 0, stream>>>(accum, out);
}